// Round 1
// 429.087 us; speedup vs baseline: 1.1452x; 1.1452x over previous
//
#include <hip/hip_runtime.h>

// Problem constants
// B=16, CI=CO=32, H=W=256, K0=K1=M=32, KAPPA=8, NPARA=7
// Kept modes: ky rows j in [0,64): ky = j (j<32) or j-64 (j>=32)
//             kx cols 0..31
//
// Pipeline (raw/unnormalized DFTs; total 1/65536 ortho factor applied at final store):
//  K1: Xw[row][kx]  = sum_w x[row][w] * e^{-2*pi*i*kx*w/256}         (row = (b,ci,h))
//  K2: Xf[p][j][kx] = sum_h Xw[p*256+h][kx] * e^{-2*pi*i*ky_j*h/256} (p = b*32+ci)
//  K3: Ff[q][j][kx] = sum_ci Xf * (W + s_b*We)    (q = b*32+co; corner-specific W/We)
//  K4 (invB, f16 MFMA): G[q][h][2kx+c] = sum_j Ff * e^{+2*pi*i*ky_j*h/256}
//  K5 (invC, f16 MFMA): out[q][h][w] = (1/65536) * sum_col G[h][col] * Ftab[col][w]

typedef _Float16 f16;
typedef _Float16 f16x8 __attribute__((ext_vector_type(8)));
typedef float f32x4 __attribute__((ext_vector_type(4)));

// Tables for the f16 inverse path:
//  Etab[h][2j]   = cos(2*pi*ky_j*h/256), Etab[h][2j+1] = sin(...)      [256][128] f16
//  Ftabt[w][2k]  = c_k*cos(2*pi*k*w/256), Ftabt[w][2k+1] = -c_k*sin()  [256][64]  f16
__global__ void k_tabs(f16* __restrict__ Etab, f16* __restrict__ Ftabt) {
    const int h = blockIdx.x;     // 0..255 (plays w for Ftabt)
    const int tid = threadIdx.x;  // 0..127
    if (tid < 64) {
        const int j = tid;
        const int ky = (j < 32) ? j : j - 64;
        float s, c;
        sincospif((float)(ky * h) / 128.0f, &s, &c);
        Etab[h * 128 + 2 * j] = (f16)c;
        Etab[h * 128 + 2 * j + 1] = (f16)s;
    } else if (tid < 96) {
        const int k = tid - 64;
        const float ck = (k == 0) ? 1.0f : 2.0f;
        float s, c;
        sincospif((float)(k * h) / 128.0f, &s, &c);
        Ftabt[h * 64 + 2 * k] = (f16)(ck * c);
        Ftabt[h * 64 + 2 * k + 1] = (f16)(-ck * s);
    }
}

// K1: row DFT. Block handles 64 rows; thread (g=tid>>5, kx=tid&31) does 8 rows for one kx.
__global__ __launch_bounds__(256) void k_rowdft(const float* __restrict__ x,
                                                float* __restrict__ Xw) {
    __shared__ __align__(16) float xs[64 * 256];  // 64 KB
    const int tid = threadIdx.x;
    const long rowbase = (long)blockIdx.x * 64;

    const float4* src = (const float4*)(x + rowbase * 256);
    float4* dst4 = (float4*)xs;
#pragma unroll
    for (int m = 0; m < 16; ++m) dst4[m * 256 + tid] = src[m * 256 + tid];
    __syncthreads();

    const int kx = tid & 31, g = tid >> 5;
    float sc, ss;
    sincospif(kx / 128.0f, &ss, &sc);  // theta = 2*pi*kx/256
    ss = -ss;                          // step = e^{-i*theta}
    float c = 1.0f, s = 0.0f;          // rot = e^{-i*theta*w}
    float accr[8] = {0}, acci[8] = {0};
    const float4* xs4 = (const float4*)xs;

    for (int w4 = 0; w4 < 64; ++w4) {
        float4 xv[8];
#pragma unroll
        for (int i = 0; i < 8; ++i) xv[i] = xs4[(g * 8 + i) * 64 + w4];
#pragma unroll
        for (int jw = 0; jw < 4; ++jw) {
#pragma unroll
            for (int i = 0; i < 8; ++i) {
                const float xvv = (&xv[i].x)[jw];
                accr[i] = fmaf(xvv, c, accr[i]);
                acci[i] = fmaf(xvv, s, acci[i]);
            }
            const float cn = c * sc - s * ss;
            s = s * sc + c * ss;
            c = cn;
        }
    }
#pragma unroll
    for (int i = 0; i < 8; ++i) {
        const long r = rowbase + g * 8 + i;
        ((float2*)(Xw + r * 64))[kx] = make_float2(accr[i], acci[i]);
    }
}

// K2: column DFT per (b,ci). Thread (ja=tid>>3, kxg=tid&7): j in {ja, ja+32}, kx = kxg*4..+3.
__global__ __launch_bounds__(256) void k_coldft(const float* __restrict__ Xw,
                                                float* __restrict__ Xf) {
    __shared__ __align__(16) float xs[256 * 64];  // [h][kx*2], 64 KB
    const int tid = threadIdx.x;
    const long p = blockIdx.x;  // b*32+ci

    const float4* src = (const float4*)(Xw + p * 16384);
    float4* dst4 = (float4*)xs;
#pragma unroll
    for (int m = 0; m < 16; ++m) dst4[m * 256 + tid] = src[m * 256 + tid];
    __syncthreads();

    const int ja = tid >> 3, kxg = tid & 7;
    float sca, ssa, scb, ssb;
    sincospif(ja / 128.0f, &ssa, &sca);          // ky_a = ja
    ssa = -ssa;
    sincospif((ja - 32) / 128.0f, &ssb, &scb);   // ky_b = ja - 32  (rows 224..255)
    ssb = -ssb;
    float ca = 1.0f, sa = 0.0f, cb = 1.0f, sb = 0.0f;
    float ar[2][4] = {{0}}, ai[2][4] = {{0}};
    const float4* xs4 = (const float4*)xs;

    for (int h = 0; h < 256; ++h) {
        const float4 u = xs4[h * 16 + kxg * 2];
        const float4 v = xs4[h * 16 + kxg * 2 + 1];
        const float xr[4] = {u.x, u.z, v.x, v.z};
        const float xi[4] = {u.y, u.w, v.y, v.w};
#pragma unroll
        for (int m = 0; m < 4; ++m) {
            ar[0][m] += xr[m] * ca - xi[m] * sa;
            ai[0][m] += xr[m] * sa + xi[m] * ca;
            ar[1][m] += xr[m] * cb - xi[m] * sb;
            ai[1][m] += xr[m] * sb + xi[m] * cb;
        }
        float t;
        t = ca * sca - sa * ssa; sa = sa * sca + ca * ssa; ca = t;
        t = cb * scb - sb * ssb; sb = sb * scb + cb * ssb; cb = t;
    }
#pragma unroll
    for (int jj = 0; jj < 2; ++jj) {
        const int j = ja + jj * 32;
        float4* o = (float4*)(Xf + ((p * 64 + j) * 32 + kxg * 4) * 2);
        o[0] = make_float4(ar[jj][0], ai[jj][0], ar[jj][1], ai[jj][1]);
        o[1] = make_float4(ar[jj][2], ai[jj][2], ar[jj][3], ai[jj][3]);
    }
}

// K3: mode mixing. Block per (j,kx): Ff[q][j][kx] = sum_ci Xf[p][j][kx]*(W + s_b*We)
__global__ __launch_bounds__(256) void k_mix(const float* __restrict__ Xf,
                                             const float* __restrict__ fs,
                                             const float* __restrict__ w0,
                                             const float* __restrict__ w1,
                                             const float* __restrict__ we0,
                                             const float* __restrict__ we1,
                                             float* __restrict__ Ff) {
    __shared__ float2 xv[512];    // [b*32+ci]
    __shared__ float2 wsw[1024];  // [ci*32+co]
    __shared__ float2 wse[1024];
    __shared__ float sv[16];
    const int tid = threadIdx.x;
    const int j = blockIdx.x >> 5, kx = blockIdx.x & 31;
    const int jj = j & 31;
    const float* W = (j < 32) ? w0 : w1;
    const float* We = (j < 32) ? we0 : we1;
    const int moff = (jj * 32 + kx) * 2;  // weight offset (per-corner row index)
    const int foff = (j * 32 + kx) * 2;   // spectrum offset (full j)

    for (int t = tid; t < 512; t += 256)
        xv[t] = *(const float2*)(Xf + (long)t * 4096 + foff);
    for (int t = tid; t < 1024; t += 256) {
        wsw[t] = *(const float2*)(W + (long)t * 2048 + moff);
        wse[t] = *(const float2*)(We + (long)t * 2048 + moff);
    }
    if (tid < 16) {
        // hierarchical quadrant index of (u=jj, v=kx); KAPPA=8, LEVEL0=3
        const int u = jj, v = kx;
        int idx;
        if (u < 8 && v < 8) idx = 0;
        else if (u < 16 && v < 16) idx = (u < 8) ? 1 : ((v < 8) ? 2 : 3);
        else idx = (u < 16) ? 4 : ((v < 16) ? 5 : 6);
        sv[tid] = fs[tid * 7 + idx];
    }
    __syncthreads();

    for (int t = tid; t < 512; t += 256) {
        const int b = t >> 5, co = t & 31;
        const float s = sv[b];
        float re = 0.0f, im = 0.0f;
#pragma unroll 8
        for (int ci = 0; ci < 32; ++ci) {
            const float2 xc = xv[b * 32 + ci];
            const float2 wc = wsw[ci * 32 + co];
            const float2 ec = wse[ci * 32 + co];
            const float mr = wc.x + s * ec.x;
            const float mi = wc.y + s * ec.y;
            re += xc.x * mr - xc.y * mi;
            im += xc.x * mi + xc.y * mr;
        }
        *(float2*)(Ff + (long)t * 4096 + foff) = make_float2(re, im);
    }
}

// K4 (invB): per q, f16 MFMA GEMM  G'[256h x 64] = Etab[256h x 128K] * F'[128K x 64n]
//   K index = (j, c_in) = 2j+c ; n index = (kx, c_out) = 2kx+c
//   F'[2j][2kx]=Fr  F'[2j][2kx+1]=Fi  F'[2j+1][2kx]=-Fi  F'[2j+1][2kx+1]=Fr
//   => G'[h][2kx] = sum_j Fr*cos - Fi*sin = Gr ; G'[h][2kx+1] = Gi   (e^{+i*theta})
// Stored to Gbuf[q][h][64] f16 (row-major), consumed as A-operand by invC.
__global__ __launch_bounds__(256) void k_invB(const float* __restrict__ Ff,
                                              const f16* __restrict__ Etab,
                                              f16* __restrict__ Gbuf) {
    __shared__ __align__(16) f16 Ft[64 * 136];   // F' transposed [n][K], pad 128->136
    __shared__ __align__(16) f16 Gs[256 * 72];   // repack buffer [h][col], pad 64->72
    const int tid = threadIdx.x;
    const long q = blockIdx.x;

    // stage F't from Ff f32 (4096 floats): thread loads 16 floats = 8 complex
    {
        const float4* src = (const float4*)(Ff + q * 4096);
        float4 v[4];
#pragma unroll
        for (int i = 0; i < 4; ++i) v[i] = src[tid * 4 + i];
#pragma unroll
        for (int i = 0; i < 4; ++i) {
            const float* f = &v[i].x;
#pragma unroll
            for (int p = 0; p < 4; p += 2) {
                const int idx = tid * 16 + i * 4 + p;  // even: (j, kx, c=0)
                const int j = idx >> 6, kx = (idx >> 1) & 31;
                const float fr = f[p], fi = f[p + 1];
                Ft[(2 * kx) * 136 + 2 * j] = (f16)fr;
                Ft[(2 * kx) * 136 + 2 * j + 1] = (f16)(-fi);
                Ft[(2 * kx + 1) * 136 + 2 * j] = (f16)fi;
                Ft[(2 * kx + 1) * 136 + 2 * j + 1] = (f16)fr;
            }
        }
    }
    __syncthreads();

    const int wv = tid >> 6, lane = tid & 63;
    const int l15 = lane & 15, lk = lane >> 4;

    f32x4 acc[4][4];
#pragma unroll
    for (int mt = 0; mt < 4; ++mt)
#pragma unroll
        for (int nt = 0; nt < 4; ++nt)
            acc[mt][nt] = (f32x4){0.0f, 0.0f, 0.0f, 0.0f};

    // A (Etab) read straight from global: 64 KB table, L2-resident.
    const f16* Arow = Etab + (wv * 64 + l15) * 128 + lk * 8;
#pragma unroll
    for (int ks = 0; ks < 4; ++ks) {
        f16x8 a[4], b[4];
#pragma unroll
        for (int mt = 0; mt < 4; ++mt)
            a[mt] = *(const f16x8*)(Arow + mt * 2048 + ks * 32);
#pragma unroll
        for (int nt = 0; nt < 4; ++nt)
            b[nt] = *(const f16x8*)(&Ft[(nt * 16 + l15) * 136 + ks * 32 + lk * 8]);
#pragma unroll
        for (int mt = 0; mt < 4; ++mt)
#pragma unroll
            for (int nt = 0; nt < 4; ++nt)
                acc[mt][nt] = __builtin_amdgcn_mfma_f32_16x16x32_f16(
                    a[mt], b[nt], acc[mt][nt], 0, 0, 0);
    }

    // D frags (row=(lane>>4)*4+r, col=lane&15) -> f16 -> Gs, wave-exclusive rows
#pragma unroll
    for (int mt = 0; mt < 4; ++mt)
#pragma unroll
        for (int nt = 0; nt < 4; ++nt) {
            const int row = wv * 64 + mt * 16 + lk * 4;
            const int col = nt * 16 + l15;
#pragma unroll
            for (int r = 0; r < 4; ++r)
                Gs[(row + r) * 72 + col] = (f16)acc[mt][nt][r];
        }
    __syncthreads();

    // coalesced copy-out: 256 rows x 64 f16 = 32 KB
#pragma unroll
    for (int p = 0; p < 8; ++p) {
        const int id = p * 256 + tid;
        const int row = id >> 3, ch = id & 7;
        const uint4 u = *(const uint4*)(Gs + row * 72 + ch * 8);
        *(uint4*)(Gbuf + q * 16384 + row * 64 + ch * 8) = u;
    }
}

// K5 (invC): per (q, half): out[128h x 256w] = G'[128h x 64col] * Ftab[64col x 256w]
//   A frags from Gbuf (global, read once); B frags from Ftabt[w][col] (32 KB, cached).
//   1/65536 ortho factor applied at the f32 store.
__global__ __launch_bounds__(256) void k_invC(const f16* __restrict__ Gbuf,
                                              const f16* __restrict__ Ftabt,
                                              float* __restrict__ out) {
    const int tid = threadIdx.x;
    const long q = blockIdx.x >> 1;
    const int half = blockIdx.x & 1;
    const int wv = tid >> 6, lane = tid & 63;
    const int l15 = lane & 15, lk = lane >> 4;

    // A frags: h = half*128 + wv*32 + mt*16 + l15 ; k(col) = ks*32 + lk*8..+7
    f16x8 a[2][2];
    const f16* abase = Gbuf + q * 16384 + (half * 128 + wv * 32 + l15) * 64 + lk * 8;
#pragma unroll
    for (int mt = 0; mt < 2; ++mt)
#pragma unroll
        for (int ks = 0; ks < 2; ++ks)
            a[mt][ks] = *(const f16x8*)(abase + mt * 1024 + ks * 32);

    float* obase = out + q * 65536 + (long)(half * 128 + wv * 32) * 256;

#pragma unroll 1
    for (int g = 0; g < 4; ++g) {  // 4 groups of 64 w-columns
        f32x4 acc[2][4];
#pragma unroll
        for (int mt = 0; mt < 2; ++mt)
#pragma unroll
            for (int nt = 0; nt < 4; ++nt)
                acc[mt][nt] = (f32x4){0.0f, 0.0f, 0.0f, 0.0f};

        const f16* bbase = Ftabt + (g * 64 + l15) * 64 + lk * 8;
#pragma unroll
        for (int nt = 0; nt < 4; ++nt)
#pragma unroll
            for (int ks = 0; ks < 2; ++ks) {
                const f16x8 b = *(const f16x8*)(bbase + nt * 1024 + ks * 32);
#pragma unroll
                for (int mt = 0; mt < 2; ++mt)
                    acc[mt][nt] = __builtin_amdgcn_mfma_f32_16x16x32_f16(
                        a[mt][ks], b, acc[mt][nt], 0, 0, 0);
            }

#pragma unroll
        for (int mt = 0; mt < 2; ++mt)
#pragma unroll
            for (int nt = 0; nt < 4; ++nt) {
                float* o = obase + (mt * 16 + lk * 4) * 256 + g * 64 + nt * 16 + l15;
#pragma unroll
                for (int r = 0; r < 4; ++r)
                    o[r * 256] = acc[mt][nt][r] * 0x1p-16f;
            }
    }
}

extern "C" void kernel_launch(void* const* d_in, const int* in_sizes, int n_in,
                              void* d_out, int out_size, void* d_ws, size_t ws_size,
                              hipStream_t stream) {
    (void)in_sizes; (void)n_in; (void)out_size; (void)ws_size;
    const float* x   = (const float*)d_in[0];
    const float* fs  = (const float*)d_in[1];
    const float* w0  = (const float*)d_in[2];
    const float* w1  = (const float*)d_in[3];
    const float* we0 = (const float*)d_in[4];
    const float* we1 = (const float*)d_in[5];
    float* out = (float*)d_out;
    float* ws = (float*)d_ws;

    f16* Etab   = (f16*)ws;               // 32768 f16 = 64 KB
    f16* Ftabt  = (f16*)(ws + 16384);     // 16384 f16 = 32 KB
    float* Xw   = ws + 24576;             // 8388608 floats [row][kx][2]
    float* Xf   = Xw + 8388608;           // 2097152 floats [p][j][kx][2]
    float* Ff   = Xf + 2097152;           // 2097152 floats [q][j][kx][2]
    f16* Gbuf   = (f16*)Xw;               // 8388608 f16, aliases Xw (dead after k_coldft)

    k_tabs  <<<256,  128, 0, stream>>>(Etab, Ftabt);
    k_rowdft<<<2048, 256, 0, stream>>>(x, Xw);
    k_coldft<<<512,  256, 0, stream>>>(Xw, Xf);
    k_mix   <<<2048, 256, 0, stream>>>(Xf, fs, w0, w1, we0, we1, Ff);
    k_invB  <<<512,  256, 0, stream>>>(Ff, Etab, Gbuf);
    k_invC  <<<1024, 256, 0, stream>>>(Gbuf, Ftabt, out);
}

// Round 2
// 360.921 us; speedup vs baseline: 1.3614x; 1.1889x over previous
//
#include <hip/hip_runtime.h>

// Problem constants
// B=16, CI=CO=32, H=W=256, K0=K1=M=32, KAPPA=8, NPARA=7
// Kept modes: ky rows j in [0,64): ky = j (j<32) or j-64 (j>=32)
//             kx cols 0..31
//
// Pipeline (raw/unnormalized DFTs; 1/65536 ortho factor applied at final store):
//  K1 (rowdftB, f16 MFMA): Xw16[row][2kx+c] = sum_w x[row][w] * Tt[2kx+c][w]
//  K2 (coldftB, f16 MFMA): Xf[p][j][2kx+c]  = sum_{h,c'} Etab2[j][2h+c'] * Bx[2h+c'][2kx+c]
//  K3: Ff[q][j][kx] = sum_ci Xf * (W + s_b*We)    (q = b*32+co; corner-specific W/We)
//  K4 (invB, f16 MFMA): G[q][h][2kx+c] = sum_j Ff * e^{+2*pi*i*ky_j*h/256}
//  K5 (invC, f16 MFMA): out[q][h][w] = (1/65536) * sum_col G[h][col] * Ftab[col][w]

typedef _Float16 f16;
typedef _Float16 f16x8 __attribute__((ext_vector_type(8)));
typedef float f32x4 __attribute__((ext_vector_type(4)));

// Tables:
//  Etab [h][2j]  = cos(2*pi*ky_j*h/256), [2j+1] = sin(...)       [256][128] f16 (invB)
//  Ftabt[w][2k]  = c_k*cos(2*pi*k*w/256), [2k+1] = -c_k*sin()    [256][64]  f16 (invC)
//  Etab2[j][2h]  = cos(2*pi*ky_j*h/256), [2h+1] = sin(...)       [64][512]  f16 (coldftB A)
//  Tt  [2kx][w]  = cos(2*pi*kx*w/256), [2kx+1][w] = -sin(...)    [64][256]  f16 (rowdftB B^T)
__global__ void k_tabs(f16* __restrict__ Etab, f16* __restrict__ Ftabt,
                       f16* __restrict__ Etab2, f16* __restrict__ Tt) {
    const int h = blockIdx.x;     // 0..255 (plays w where relevant)
    const int tid = threadIdx.x;  // 0..127
    if (tid < 64) {
        const int j = tid;
        const int ky = (j < 32) ? j : j - 64;
        float s, c;
        sincospif((float)(ky * h) / 128.0f, &s, &c);
        Etab[h * 128 + 2 * j] = (f16)c;
        Etab[h * 128 + 2 * j + 1] = (f16)s;
        Etab2[j * 512 + 2 * h] = (f16)c;
        Etab2[j * 512 + 2 * h + 1] = (f16)s;
    } else if (tid < 96) {
        const int k = tid - 64;
        const float ck = (k == 0) ? 1.0f : 2.0f;
        float s, c;
        sincospif((float)(k * h) / 128.0f, &s, &c);
        Ftabt[h * 64 + 2 * k] = (f16)(ck * c);
        Ftabt[h * 64 + 2 * k + 1] = (f16)(-ck * s);
    } else {
        const int kx = tid - 96;
        float s, c;
        sincospif((float)(kx * h) / 128.0f, &s, &c);
        Tt[(2 * kx) * 256 + h] = (f16)c;
        Tt[(2 * kx + 1) * 256 + h] = (f16)(-s);
    }
}

// K1 (rowdftB): Xw16[131072 rows x 64] = x_f16[rows x 256] * Tt^T.
// Block: 128 rows, 4 waves (wave = 32 rows = 2 m-tiles). A-frags straight from
// global x (f32->f16 in reg); B-frags straight from global Tt (32 KB, L1-hot).
// D repacked through 22 KB LDS so the f16 store is coalesced uint4.
__global__ __launch_bounds__(256) void k_rowdftB(const float* __restrict__ x,
                                                 const f16* __restrict__ Tt,
                                                 f16* __restrict__ Xw16) {
    __shared__ __align__(16) f16 Gs[128 * 88];  // stride 88 f16 = 176 B (11x16B, odd)
    const int tid = threadIdx.x;
    const int wv = tid >> 6, lane = tid & 63;
    const int l15 = lane & 15, lk = lane >> 4;
    const long rowbase = (long)blockIdx.x * 128;

    f32x4 acc[2][4];
#pragma unroll
    for (int mt = 0; mt < 2; ++mt)
#pragma unroll
        for (int nt = 0; nt < 4; ++nt)
            acc[mt][nt] = (f32x4){0.0f, 0.0f, 0.0f, 0.0f};

    const float* xbase = x + (rowbase + wv * 32 + l15) * 256 + lk * 8;
    const f16* tbase = Tt + l15 * 256 + lk * 8;

#pragma unroll
    for (int ks = 0; ks < 8; ++ks) {
        f16x8 a[2], b[4];
#pragma unroll
        for (int mt = 0; mt < 2; ++mt) {
            const float4 u = *(const float4*)(xbase + mt * 4096 + ks * 32);
            const float4 v = *(const float4*)(xbase + mt * 4096 + ks * 32 + 4);
            a[mt][0] = (f16)u.x; a[mt][1] = (f16)u.y;
            a[mt][2] = (f16)u.z; a[mt][3] = (f16)u.w;
            a[mt][4] = (f16)v.x; a[mt][5] = (f16)v.y;
            a[mt][6] = (f16)v.z; a[mt][7] = (f16)v.w;
        }
#pragma unroll
        for (int nt = 0; nt < 4; ++nt)
            b[nt] = *(const f16x8*)(tbase + nt * 4096 + ks * 32);
#pragma unroll
        for (int mt = 0; mt < 2; ++mt)
#pragma unroll
            for (int nt = 0; nt < 4; ++nt)
                acc[mt][nt] = __builtin_amdgcn_mfma_f32_16x16x32_f16(
                    a[mt], b[nt], acc[mt][nt], 0, 0, 0);
    }

    // D frags (col = lane&15, row = (lane>>4)*4 + r) -> f16 repack
#pragma unroll
    for (int mt = 0; mt < 2; ++mt)
#pragma unroll
        for (int nt = 0; nt < 4; ++nt) {
            const int row0 = wv * 32 + mt * 16 + lk * 4;
            const int col = nt * 16 + l15;
#pragma unroll
            for (int r = 0; r < 4; ++r)
                Gs[(row0 + r) * 88 + col] = (f16)acc[mt][nt][r];
        }
    __syncthreads();

    // coalesced copy-out: 128 rows x 64 f16 = 16 KB
#pragma unroll
    for (int p = 0; p < 4; ++p) {
        const int id = p * 256 + tid;
        const int row = id >> 3, ch = id & 7;
        *(uint4*)(Xw16 + (rowbase + row) * 64 + ch * 8) =
            *(const uint4*)(Gs + row * 88 + ch * 8);
    }
}

// K2 (coldftB): per p, Xf[64j x 64n] = Etab2[64j x 512K] * Bx[512K x 64n]
//   Bx^T built in LDS from Xw16: row 2kx = (Xr,Xi) pairs, row 2kx+1 = (Xi,-Xr).
//   Out[j][2kx]   = sum_h Xr*cos + Xi*sin  = Re(Xf)
//   Out[j][2kx+1] = sum_h Xi*cos - Xr*sin  = Im(Xf)      (e^{-i*theta})
// Output f32 in the existing [p][j][kx][2] layout (k_mix unchanged).
__global__ __launch_bounds__(256) void k_coldftB(const f16* __restrict__ Xw16,
                                                 const f16* __restrict__ Etab2,
                                                 float* __restrict__ Xf) {
    __shared__ __align__(16) f16 Bt[64 * 520];  // stride 520 f16 = 1040 B (65x16B, odd)
    const int tid = threadIdx.x;
    const long p = blockIdx.x;

    {   // build Bt: thread handles h = tid (reads one 128 B Xw16 row)
        const uint* src = (const uint*)(Xw16 + (p * 256 + tid) * 64);
        uint* B32 = (uint*)Bt;
#pragma unroll
        for (int kx = 0; kx < 32; ++kx) {
            const uint a = src[kx];  // (Xr, Xi) packed f16x2
            const uint b = (a >> 16) | (((a & 0xffffu) ^ 0x8000u) << 16);  // (Xi, -Xr)
            B32[(2 * kx) * 260 + tid] = a;
            B32[(2 * kx + 1) * 260 + tid] = b;
        }
    }
    __syncthreads();

    const int wv = tid >> 6, lane = tid & 63;
    const int l15 = lane & 15, lk = lane >> 4;

    f32x4 acc[4];
#pragma unroll
    for (int nt = 0; nt < 4; ++nt) acc[nt] = (f32x4){0.0f, 0.0f, 0.0f, 0.0f};

    const f16* abase = Etab2 + (wv * 16 + l15) * 512 + lk * 8;  // A from global (L2)
#pragma unroll
    for (int ks = 0; ks < 16; ++ks) {
        const f16x8 a = *(const f16x8*)(abase + ks * 32);
        f16x8 b[4];
#pragma unroll
        for (int nt = 0; nt < 4; ++nt)
            b[nt] = *(const f16x8*)(Bt + (nt * 16 + l15) * 520 + ks * 32 + lk * 8);
#pragma unroll
        for (int nt = 0; nt < 4; ++nt)
            acc[nt] = __builtin_amdgcn_mfma_f32_16x16x32_f16(a, b[nt], acc[nt], 0, 0, 0);
    }

    float* obase = Xf + p * 4096;
#pragma unroll
    for (int nt = 0; nt < 4; ++nt)
#pragma unroll
        for (int r = 0; r < 4; ++r)
            obase[(wv * 16 + lk * 4 + r) * 64 + nt * 16 + l15] = acc[nt][r];
}

// K3: mode mixing. Block per (j,kx): Ff[q][j][kx] = sum_ci Xf[p][j][kx]*(W + s_b*We)
__global__ __launch_bounds__(256) void k_mix(const float* __restrict__ Xf,
                                             const float* __restrict__ fs,
                                             const float* __restrict__ w0,
                                             const float* __restrict__ w1,
                                             const float* __restrict__ we0,
                                             const float* __restrict__ we1,
                                             float* __restrict__ Ff) {
    __shared__ float2 xv[512];    // [b*32+ci]
    __shared__ float2 wsw[1024];  // [ci*32+co]
    __shared__ float2 wse[1024];
    __shared__ float sv[16];
    const int tid = threadIdx.x;
    const int j = blockIdx.x >> 5, kx = blockIdx.x & 31;
    const int jj = j & 31;
    const float* W = (j < 32) ? w0 : w1;
    const float* We = (j < 32) ? we0 : we1;
    const int moff = (jj * 32 + kx) * 2;  // weight offset (per-corner row index)
    const int foff = (j * 32 + kx) * 2;   // spectrum offset (full j)

    for (int t = tid; t < 512; t += 256)
        xv[t] = *(const float2*)(Xf + (long)t * 4096 + foff);
    for (int t = tid; t < 1024; t += 256) {
        wsw[t] = *(const float2*)(W + (long)t * 2048 + moff);
        wse[t] = *(const float2*)(We + (long)t * 2048 + moff);
    }
    if (tid < 16) {
        // hierarchical quadrant index of (u=jj, v=kx); KAPPA=8, LEVEL0=3
        const int u = jj, v = kx;
        int idx;
        if (u < 8 && v < 8) idx = 0;
        else if (u < 16 && v < 16) idx = (u < 8) ? 1 : ((v < 8) ? 2 : 3);
        else idx = (u < 16) ? 4 : ((v < 16) ? 5 : 6);
        sv[tid] = fs[tid * 7 + idx];
    }
    __syncthreads();

    for (int t = tid; t < 512; t += 256) {
        const int b = t >> 5, co = t & 31;
        const float s = sv[b];
        float re = 0.0f, im = 0.0f;
#pragma unroll 8
        for (int ci = 0; ci < 32; ++ci) {
            const float2 xc = xv[b * 32 + ci];
            const float2 wc = wsw[ci * 32 + co];
            const float2 ec = wse[ci * 32 + co];
            const float mr = wc.x + s * ec.x;
            const float mi = wc.y + s * ec.y;
            re += xc.x * mr - xc.y * mi;
            im += xc.x * mi + xc.y * mr;
        }
        *(float2*)(Ff + (long)t * 4096 + foff) = make_float2(re, im);
    }
}

// K4 (invB): per q, f16 MFMA GEMM  G'[256h x 64] = Etab[256h x 128K] * F'[128K x 64n]
__global__ __launch_bounds__(256) void k_invB(const float* __restrict__ Ff,
                                              const f16* __restrict__ Etab,
                                              f16* __restrict__ Gbuf) {
    __shared__ __align__(16) f16 Ft[64 * 136];   // F' transposed [n][K], pad 128->136
    __shared__ __align__(16) f16 Gs[256 * 72];   // repack buffer [h][col], pad 64->72
    const int tid = threadIdx.x;
    const long q = blockIdx.x;

    // stage F't from Ff f32 (4096 floats): thread loads 16 floats = 8 complex
    {
        const float4* src = (const float4*)(Ff + q * 4096);
        float4 v[4];
#pragma unroll
        for (int i = 0; i < 4; ++i) v[i] = src[tid * 4 + i];
#pragma unroll
        for (int i = 0; i < 4; ++i) {
            const float* f = &v[i].x;
#pragma unroll
            for (int p = 0; p < 4; p += 2) {
                const int idx = tid * 16 + i * 4 + p;  // even: (j, kx, c=0)
                const int j = idx >> 6, kx = (idx >> 1) & 31;
                const float fr = f[p], fi = f[p + 1];
                Ft[(2 * kx) * 136 + 2 * j] = (f16)fr;
                Ft[(2 * kx) * 136 + 2 * j + 1] = (f16)(-fi);
                Ft[(2 * kx + 1) * 136 + 2 * j] = (f16)fi;
                Ft[(2 * kx + 1) * 136 + 2 * j + 1] = (f16)fr;
            }
        }
    }
    __syncthreads();

    const int wv = tid >> 6, lane = tid & 63;
    const int l15 = lane & 15, lk = lane >> 4;

    f32x4 acc[4][4];
#pragma unroll
    for (int mt = 0; mt < 4; ++mt)
#pragma unroll
        for (int nt = 0; nt < 4; ++nt)
            acc[mt][nt] = (f32x4){0.0f, 0.0f, 0.0f, 0.0f};

    const f16* Arow = Etab + (wv * 64 + l15) * 128 + lk * 8;
#pragma unroll
    for (int ks = 0; ks < 4; ++ks) {
        f16x8 a[4], b[4];
#pragma unroll
        for (int mt = 0; mt < 4; ++mt)
            a[mt] = *(const f16x8*)(Arow + mt * 2048 + ks * 32);
#pragma unroll
        for (int nt = 0; nt < 4; ++nt)
            b[nt] = *(const f16x8*)(&Ft[(nt * 16 + l15) * 136 + ks * 32 + lk * 8]);
#pragma unroll
        for (int mt = 0; mt < 4; ++mt)
#pragma unroll
            for (int nt = 0; nt < 4; ++nt)
                acc[mt][nt] = __builtin_amdgcn_mfma_f32_16x16x32_f16(
                    a[mt], b[nt], acc[mt][nt], 0, 0, 0);
    }

#pragma unroll
    for (int mt = 0; mt < 4; ++mt)
#pragma unroll
        for (int nt = 0; nt < 4; ++nt) {
            const int row = wv * 64 + mt * 16 + lk * 4;
            const int col = nt * 16 + l15;
#pragma unroll
            for (int r = 0; r < 4; ++r)
                Gs[(row + r) * 72 + col] = (f16)acc[mt][nt][r];
        }
    __syncthreads();

#pragma unroll
    for (int p = 0; p < 8; ++p) {
        const int id = p * 256 + tid;
        const int row = id >> 3, ch = id & 7;
        const uint4 u = *(const uint4*)(Gs + row * 72 + ch * 8);
        *(uint4*)(Gbuf + q * 16384 + row * 64 + ch * 8) = u;
    }
}

// K5 (invC): per (q, half): out[128h x 256w] = G'[128h x 64col] * Ftab[64col x 256w]
__global__ __launch_bounds__(256) void k_invC(const f16* __restrict__ Gbuf,
                                              const f16* __restrict__ Ftabt,
                                              float* __restrict__ out) {
    const int tid = threadIdx.x;
    const long q = blockIdx.x >> 1;
    const int half = blockIdx.x & 1;
    const int wv = tid >> 6, lane = tid & 63;
    const int l15 = lane & 15, lk = lane >> 4;

    f16x8 a[2][2];
    const f16* abase = Gbuf + q * 16384 + (half * 128 + wv * 32 + l15) * 64 + lk * 8;
#pragma unroll
    for (int mt = 0; mt < 2; ++mt)
#pragma unroll
        for (int ks = 0; ks < 2; ++ks)
            a[mt][ks] = *(const f16x8*)(abase + mt * 1024 + ks * 32);

    float* obase = out + q * 65536 + (long)(half * 128 + wv * 32) * 256;

#pragma unroll 1
    for (int g = 0; g < 4; ++g) {  // 4 groups of 64 w-columns
        f32x4 acc[2][4];
#pragma unroll
        for (int mt = 0; mt < 2; ++mt)
#pragma unroll
            for (int nt = 0; nt < 4; ++nt)
                acc[mt][nt] = (f32x4){0.0f, 0.0f, 0.0f, 0.0f};

        const f16* bbase = Ftabt + (g * 64 + l15) * 64 + lk * 8;
#pragma unroll
        for (int nt = 0; nt < 4; ++nt)
#pragma unroll
            for (int ks = 0; ks < 2; ++ks) {
                const f16x8 b = *(const f16x8*)(bbase + nt * 1024 + ks * 32);
#pragma unroll
                for (int mt = 0; mt < 2; ++mt)
                    acc[mt][nt] = __builtin_amdgcn_mfma_f32_16x16x32_f16(
                        a[mt][ks], b, acc[mt][nt], 0, 0, 0);
            }

#pragma unroll
        for (int mt = 0; mt < 2; ++mt)
#pragma unroll
            for (int nt = 0; nt < 4; ++nt) {
                float* o = obase + (mt * 16 + lk * 4) * 256 + g * 64 + nt * 16 + l15;
#pragma unroll
                for (int r = 0; r < 4; ++r)
                    o[r * 256] = acc[mt][nt][r] * 0x1p-16f;
            }
    }
}

extern "C" void kernel_launch(void* const* d_in, const int* in_sizes, int n_in,
                              void* d_out, int out_size, void* d_ws, size_t ws_size,
                              hipStream_t stream) {
    (void)in_sizes; (void)n_in; (void)out_size; (void)ws_size;
    const float* x   = (const float*)d_in[0];
    const float* fs  = (const float*)d_in[1];
    const float* w0  = (const float*)d_in[2];
    const float* w1  = (const float*)d_in[3];
    const float* we0 = (const float*)d_in[4];
    const float* we1 = (const float*)d_in[5];
    float* out = (float*)d_out;
    float* ws = (float*)d_ws;

    f16* Etab   = (f16*)ws;                        // 32768 f16 (64 KB)
    f16* Ftabt  = (f16*)(ws + 16384);              // 16384 f16 (32 KB)
    f16* Etab2  = (f16*)(ws + 24576);              // 32768 f16 (64 KB)
    f16* Tt     = (f16*)(ws + 40960);              // 16384 f16 (32 KB)
    f16* Xw16   = (f16*)(ws + 49152);              // 8388608 f16 (16 MB)
    f16* Gbuf   = (f16*)(ws + 49152 + 4194304);    // 8388608 f16 (16 MB)
    float* Xf   = ws + 49152 + 8388608;            // 2097152 floats [p][j][kx][2]
    float* Ff   = Xf + 2097152;                    // 2097152 floats [q][j][kx][2]

    k_tabs   <<<256,  128, 0, stream>>>(Etab, Ftabt, Etab2, Tt);
    k_rowdftB<<<1024, 256, 0, stream>>>(x, Tt, Xw16);
    k_coldftB<<<512,  256, 0, stream>>>(Xw16, Etab2, Xf);
    k_mix    <<<2048, 256, 0, stream>>>(Xf, fs, w0, w1, we0, we1, Ff);
    k_invB   <<<512,  256, 0, stream>>>(Ff, Etab, Gbuf);
    k_invC   <<<1024, 256, 0, stream>>>(Gbuf, Ftabt, out);
}

// Round 3
// 319.692 us; speedup vs baseline: 1.5370x; 1.1290x over previous
//
#include <hip/hip_runtime.h>

// Problem constants
// B=16, CI=CO=32, H=W=256, K0=K1=M=32, KAPPA=8, NPARA=7
// Kept modes: ky rows j in [0,64): ky = j (j<32) or j-64 (j>=32)
//             kx cols 0..31
//
// Pipeline (raw/unnormalized DFTs; 1/65536 ortho factor applied at final store):
//  K1 (rowdftB, f16 MFMA): Xw16[row][2kx+c] = sum_w x[row][w] * Tt[2kx+c][w]
//  K2 (coldftB, f16 MFMA): Xf16[p][j][kx]   = sum_h Xw16 * e^{-2*pi*i*ky_j*h/256}
//  K3 (mixB, f32 VALU):    Ff16[q][j][kx]   = sum_ci Xf16 * (W + s_b*We)
//  K4 (invB, f16 MFMA):    Gbuf[q][h][2kx+c]= sum_j Ff16 * e^{+2*pi*i*ky_j*h/256}
//  K5 (invC, f16 MFMA):    out[q][h][w] = (1/65536) * sum_col Gbuf * Ftab[col][w]

typedef _Float16 f16;
typedef _Float16 f16x8 __attribute__((ext_vector_type(8)));
typedef float f32x4 __attribute__((ext_vector_type(4)));

static __device__ __forceinline__ float2 upk(uint u) {
    union { uint x; f16 h[2]; } c; c.x = u;
    return make_float2((float)c.h[0], (float)c.h[1]);
}
static __device__ __forceinline__ uint pk2(float r, float i) {
    union { uint x; f16 h[2]; } c; c.h[0] = (f16)r; c.h[1] = (f16)i;
    return c.x;
}

// Tables:
//  Etab [h][2j]  = cos(2*pi*ky_j*h/256), [2j+1] = sin(...)       [256][128] f16 (invB)
//  Ftabt[w][2k]  = c_k*cos(2*pi*k*w/256), [2k+1] = -c_k*sin()    [256][64]  f16 (invC)
//  Etab2[j][2h]  = cos(2*pi*ky_j*h/256), [2h+1] = sin(...)       [64][512]  f16 (coldftB A)
//  Tt  [2kx][w]  = cos(2*pi*kx*w/256), [2kx+1][w] = -sin(...)    [64][256]  f16 (rowdftB B^T)
__global__ void k_tabs(f16* __restrict__ Etab, f16* __restrict__ Ftabt,
                       f16* __restrict__ Etab2, f16* __restrict__ Tt) {
    const int h = blockIdx.x;     // 0..255 (plays w where relevant)
    const int tid = threadIdx.x;  // 0..127
    if (tid < 64) {
        const int j = tid;
        const int ky = (j < 32) ? j : j - 64;
        float s, c;
        sincospif((float)(ky * h) / 128.0f, &s, &c);
        Etab[h * 128 + 2 * j] = (f16)c;
        Etab[h * 128 + 2 * j + 1] = (f16)s;
        Etab2[j * 512 + 2 * h] = (f16)c;
        Etab2[j * 512 + 2 * h + 1] = (f16)s;
    } else if (tid < 96) {
        const int k = tid - 64;
        const float ck = (k == 0) ? 1.0f : 2.0f;
        float s, c;
        sincospif((float)(k * h) / 128.0f, &s, &c);
        Ftabt[h * 64 + 2 * k] = (f16)(ck * c);
        Ftabt[h * 64 + 2 * k + 1] = (f16)(-ck * s);
    } else {
        const int kx = tid - 96;
        float s, c;
        sincospif((float)(kx * h) / 128.0f, &s, &c);
        Tt[(2 * kx) * 256 + h] = (f16)c;
        Tt[(2 * kx + 1) * 256 + h] = (f16)(-s);
    }
}

// K1 (rowdftB): Xw16[131072 rows x 64] = x_f16[rows x 256] * Tt^T.
__global__ __launch_bounds__(256) void k_rowdftB(const float* __restrict__ x,
                                                 const f16* __restrict__ Tt,
                                                 f16* __restrict__ Xw16) {
    __shared__ __align__(16) f16 Gs[128 * 88];  // stride 88 f16 = 176 B (odd 16B count)
    const int tid = threadIdx.x;
    const int wv = tid >> 6, lane = tid & 63;
    const int l15 = lane & 15, lk = lane >> 4;
    const long rowbase = (long)blockIdx.x * 128;

    f32x4 acc[2][4];
#pragma unroll
    for (int mt = 0; mt < 2; ++mt)
#pragma unroll
        for (int nt = 0; nt < 4; ++nt)
            acc[mt][nt] = (f32x4){0.0f, 0.0f, 0.0f, 0.0f};

    const float* xbase = x + (rowbase + wv * 32 + l15) * 256 + lk * 8;
    const f16* tbase = Tt + l15 * 256 + lk * 8;

#pragma unroll
    for (int ks = 0; ks < 8; ++ks) {
        f16x8 a[2], b[4];
#pragma unroll
        for (int mt = 0; mt < 2; ++mt) {
            const float4 u = *(const float4*)(xbase + mt * 4096 + ks * 32);
            const float4 v = *(const float4*)(xbase + mt * 4096 + ks * 32 + 4);
            a[mt][0] = (f16)u.x; a[mt][1] = (f16)u.y;
            a[mt][2] = (f16)u.z; a[mt][3] = (f16)u.w;
            a[mt][4] = (f16)v.x; a[mt][5] = (f16)v.y;
            a[mt][6] = (f16)v.z; a[mt][7] = (f16)v.w;
        }
#pragma unroll
        for (int nt = 0; nt < 4; ++nt)
            b[nt] = *(const f16x8*)(tbase + nt * 4096 + ks * 32);
#pragma unroll
        for (int mt = 0; mt < 2; ++mt)
#pragma unroll
            for (int nt = 0; nt < 4; ++nt)
                acc[mt][nt] = __builtin_amdgcn_mfma_f32_16x16x32_f16(
                    a[mt], b[nt], acc[mt][nt], 0, 0, 0);
    }

#pragma unroll
    for (int mt = 0; mt < 2; ++mt)
#pragma unroll
        for (int nt = 0; nt < 4; ++nt) {
            const int row0 = wv * 32 + mt * 16 + lk * 4;
            const int col = nt * 16 + l15;
#pragma unroll
            for (int r = 0; r < 4; ++r)
                Gs[(row0 + r) * 88 + col] = (f16)acc[mt][nt][r];
        }
    __syncthreads();

#pragma unroll
    for (int p = 0; p < 4; ++p) {
        const int id = p * 256 + tid;
        const int row = id >> 3, ch = id & 7;
        *(uint4*)(Xw16 + (rowbase + row) * 64 + ch * 8) =
            *(const uint4*)(Gs + row * 88 + ch * 8);
    }
}

// K2 (coldftB): per p, Xf16[64j x 64n] = Etab2[64j x 512K] * Bx[512K x 64n]
//   Bx^T built in LDS from Xw16: row 2kx = (Xr,Xi) pairs, row 2kx+1 = (Xi,-Xr).
// Output PACKED f16 in [p][j][kx]{re,im} layout (one u32 per mode).
__global__ __launch_bounds__(256) void k_coldftB(const f16* __restrict__ Xw16,
                                                 const f16* __restrict__ Etab2,
                                                 f16* __restrict__ Xf16) {
    __shared__ __align__(16) f16 Bt[64 * 520];  // stride 520 f16 (odd 16B count)
    const int tid = threadIdx.x;
    const long p = blockIdx.x;

    {   // build Bt: thread handles h = tid (reads one 128 B Xw16 row)
        const uint* src = (const uint*)(Xw16 + (p * 256 + tid) * 64);
        uint* B32 = (uint*)Bt;
#pragma unroll
        for (int kx = 0; kx < 32; ++kx) {
            const uint a = src[kx];  // (Xr, Xi) packed f16x2
            const uint b = (a >> 16) | (((a & 0xffffu) ^ 0x8000u) << 16);  // (Xi, -Xr)
            B32[(2 * kx) * 260 + tid] = a;
            B32[(2 * kx + 1) * 260 + tid] = b;
        }
    }
    __syncthreads();

    const int wv = tid >> 6, lane = tid & 63;
    const int l15 = lane & 15, lk = lane >> 4;

    f32x4 acc[4];
#pragma unroll
    for (int nt = 0; nt < 4; ++nt) acc[nt] = (f32x4){0.0f, 0.0f, 0.0f, 0.0f};

    const f16* abase = Etab2 + (wv * 16 + l15) * 512 + lk * 8;  // A from global (L2)
#pragma unroll
    for (int ks = 0; ks < 16; ++ks) {
        const f16x8 a = *(const f16x8*)(abase + ks * 32);
        f16x8 b[4];
#pragma unroll
        for (int nt = 0; nt < 4; ++nt)
            b[nt] = *(const f16x8*)(Bt + (nt * 16 + l15) * 520 + ks * 32 + lk * 8);
#pragma unroll
        for (int nt = 0; nt < 4; ++nt)
            acc[nt] = __builtin_amdgcn_mfma_f32_16x16x32_f16(a, b[nt], acc[nt], 0, 0, 0);
    }

    // store f16 scalars: n = nt*16+l15 (even=re, odd=im), row j = wv*16+lk*4+r
    f16* obase = Xf16 + p * 4096;
#pragma unroll
    for (int nt = 0; nt < 4; ++nt)
#pragma unroll
        for (int r = 0; r < 4; ++r)
            obase[(wv * 16 + lk * 4 + r) * 64 + nt * 16 + l15] = (f16)acc[nt][r];
}

// K3 (mixB): block = (cog 8)*(corner 2)*(jj 32) = 512 blocks.
//   Ff[q=(b, cog*4+co)][j][kx] = sum_ci Xf[(b,ci)][j][kx] * (W + s(b,jj,kx)*We)[ci,co,jj,kx]
// Weight slice (32ci x 4co x 32kx x {re,im} x 2 tensors = 64 KB f32) staged in LDS,
// read ONCE, coalesced (contiguous 256 B rows). XOR-16 float4 swizzle for bank-free reads.
// X streamed from global; the 8 cog-sharers of an X-tile land on the same XCD
// (blockIdx differs by 64 == 0 mod 8) -> L2 hits.
__global__ __launch_bounds__(256) void k_mixB(const f16* __restrict__ Xf16,
                                              const float* __restrict__ fs,
                                              const float* __restrict__ w0,
                                              const float* __restrict__ w1,
                                              const float* __restrict__ we0,
                                              const float* __restrict__ we1,
                                              f16* __restrict__ Ff16) {
    __shared__ __align__(16) float4 Wl[4096];  // 64 KB: rows 0..127 = W, 128..255 = We
    const int tid = threadIdx.x;
    const int bid = blockIdx.x;
    const int cog = bid >> 6;            // 0..7 (co group of 4)
    const int corner = (bid >> 5) & 1;
    const int jj = bid & 31;
    const int j = corner * 32 + jj;

    {   // stage: thread = row tid: t = tid>>7 (0:W 1:We), ci = (tid>>2)&31, co = tid&3
        const int t = tid >> 7, ci = (tid >> 2) & 31, co = tid & 3;
        const float* Wt = (t == 0) ? (corner ? w1 : w0) : (corner ? we1 : we0);
        const float4* src =
            (const float4*)(Wt + ((long)(ci * 32 + cog * 4 + co) * 2048 + jj * 64));
        const int m = tid & 15;
#pragma unroll
        for (int i = 0; i < 16; ++i) Wl[tid * 16 + (i ^ m)] = src[i];
    }
    __syncthreads();

    const int b = tid >> 4, kxp = tid & 15;
    const int kx0 = 2 * kxp;

    float s[2];
#pragma unroll
    for (int e = 0; e < 2; ++e) {
        const int v = kx0 + e, u = jj;
        int idx;
        if (u < 8 && v < 8) idx = 0;
        else if (u < 16 && v < 16) idx = (u < 8) ? 1 : ((v < 8) ? 2 : 3);
        else idx = (u < 16) ? 4 : ((v < 16) ? 5 : 6);
        s[e] = fs[b * 7 + idx];
    }

    float aW[4][4] = {}, aE[4][4] = {};  // [co][{re0,im0,re1,im1}]
    const uint* xb = (const uint*)Xf16 + (long)(b * 32) * 2048 + j * 32 + kx0;

    for (int ci = 0; ci < 32; ++ci) {
        const uint2 xu = *(const uint2*)(xb + ci * 2048);
        const float2 x0 = upk(xu.x), x1 = upk(xu.y);
        const int rbase = ci * 4;
#pragma unroll
        for (int co = 0; co < 4; ++co) {
            const int rw = rbase + co;
            const int sl = kxp ^ (rw & 15);
            const float4 wv = Wl[rw * 16 + sl];
            const float4 ev = Wl[(128 + rw) * 16 + sl];
            aW[co][0] += x0.x * wv.x - x0.y * wv.y;
            aW[co][1] += x0.x * wv.y + x0.y * wv.x;
            aW[co][2] += x1.x * wv.z - x1.y * wv.w;
            aW[co][3] += x1.x * wv.w + x1.y * wv.z;
            aE[co][0] += x0.x * ev.x - x0.y * ev.y;
            aE[co][1] += x0.x * ev.y + x0.y * ev.x;
            aE[co][2] += x1.x * ev.z - x1.y * ev.w;
            aE[co][3] += x1.x * ev.w + x1.y * ev.z;
        }
    }

    uint* ofb = (uint*)Ff16;
#pragma unroll
    for (int co = 0; co < 4; ++co) {
        const long q = b * 32 + cog * 4 + co;
        uint2 o;
        o.x = pk2(aW[co][0] + s[0] * aE[co][0], aW[co][1] + s[0] * aE[co][1]);
        o.y = pk2(aW[co][2] + s[1] * aE[co][2], aW[co][3] + s[1] * aE[co][3]);
        *(uint2*)(ofb + q * 2048 + j * 32 + kx0) = o;
    }
}

// K4 (invB): per q, f16 MFMA GEMM  G'[256h x 64] = Etab[256h x 128K] * F'[128K x 64n]
//   F' realified from packed Ff16 via u32 tricks: (-im) = a^0x80000000, swap = rotate16.
__global__ __launch_bounds__(256) void k_invB(const f16* __restrict__ Ff16,
                                              const f16* __restrict__ Etab,
                                              f16* __restrict__ Gbuf) {
    __shared__ __align__(16) f16 Ft[64 * 136];   // F' transposed [n][K], pad 128->136
    __shared__ __align__(16) f16 Gs[256 * 72];   // repack buffer [h][col], pad 64->72
    const int tid = threadIdx.x;
    const long q = blockIdx.x;

    {   // stage F't from packed Ff16 (2048 u32 per q): thread handles 16 u32
        const uint4* src = (const uint4*)(Ff16 + q * 4096);
        uint* B32 = (uint*)Ft;
#pragma unroll
        for (int i = 0; i < 2; ++i) {
            const uint4 v = src[tid * 2 + i];
            const uint a4[4] = {v.x, v.y, v.z, v.w};
#pragma unroll
            for (int c = 0; c < 4; ++c) {
                const int idx = tid * 8 + i * 4 + c;  // u32 idx: j = idx>>5, kx = idx&31
                const int jr = idx >> 5, kx = idx & 31;
                const uint a = a4[c];
                B32[(2 * kx) * 68 + jr] = a ^ 0x80000000u;          // (re, -im)
                B32[(2 * kx + 1) * 68 + jr] = (a >> 16) | (a << 16); // (im,  re)
            }
        }
    }
    __syncthreads();

    const int wv = tid >> 6, lane = tid & 63;
    const int l15 = lane & 15, lk = lane >> 4;

    f32x4 acc[4][4];
#pragma unroll
    for (int mt = 0; mt < 4; ++mt)
#pragma unroll
        for (int nt = 0; nt < 4; ++nt)
            acc[mt][nt] = (f32x4){0.0f, 0.0f, 0.0f, 0.0f};

    const f16* Arow = Etab + (wv * 64 + l15) * 128 + lk * 8;
#pragma unroll
    for (int ks = 0; ks < 4; ++ks) {
        f16x8 a[4], b[4];
#pragma unroll
        for (int mt = 0; mt < 4; ++mt)
            a[mt] = *(const f16x8*)(Arow + mt * 2048 + ks * 32);
#pragma unroll
        for (int nt = 0; nt < 4; ++nt)
            b[nt] = *(const f16x8*)(&Ft[(nt * 16 + l15) * 136 + ks * 32 + lk * 8]);
#pragma unroll
        for (int mt = 0; mt < 4; ++mt)
#pragma unroll
            for (int nt = 0; nt < 4; ++nt)
                acc[mt][nt] = __builtin_amdgcn_mfma_f32_16x16x32_f16(
                    a[mt], b[nt], acc[mt][nt], 0, 0, 0);
    }

#pragma unroll
    for (int mt = 0; mt < 4; ++mt)
#pragma unroll
        for (int nt = 0; nt < 4; ++nt) {
            const int row = wv * 64 + mt * 16 + lk * 4;
            const int col = nt * 16 + l15;
#pragma unroll
            for (int r = 0; r < 4; ++r)
                Gs[(row + r) * 72 + col] = (f16)acc[mt][nt][r];
        }
    __syncthreads();

#pragma unroll
    for (int p = 0; p < 8; ++p) {
        const int id = p * 256 + tid;
        const int row = id >> 3, ch = id & 7;
        const uint4 u = *(const uint4*)(Gs + row * 72 + ch * 8);
        *(uint4*)(Gbuf + q * 16384 + row * 64 + ch * 8) = u;
    }
}

// K5 (invC): per (q, half): out[128h x 256w] = G'[128h x 64col] * Ftab[64col x 256w]
__global__ __launch_bounds__(256) void k_invC(const f16* __restrict__ Gbuf,
                                              const f16* __restrict__ Ftabt,
                                              float* __restrict__ out) {
    const int tid = threadIdx.x;
    const long q = blockIdx.x >> 1;
    const int half = blockIdx.x & 1;
    const int wv = tid >> 6, lane = tid & 63;
    const int l15 = lane & 15, lk = lane >> 4;

    f16x8 a[2][2];
    const f16* abase = Gbuf + q * 16384 + (half * 128 + wv * 32 + l15) * 64 + lk * 8;
#pragma unroll
    for (int mt = 0; mt < 2; ++mt)
#pragma unroll
        for (int ks = 0; ks < 2; ++ks)
            a[mt][ks] = *(const f16x8*)(abase + mt * 1024 + ks * 32);

    float* obase = out + q * 65536 + (long)(half * 128 + wv * 32) * 256;

#pragma unroll 1
    for (int g = 0; g < 4; ++g) {  // 4 groups of 64 w-columns
        f32x4 acc[2][4];
#pragma unroll
        for (int mt = 0; mt < 2; ++mt)
#pragma unroll
            for (int nt = 0; nt < 4; ++nt)
                acc[mt][nt] = (f32x4){0.0f, 0.0f, 0.0f, 0.0f};

        const f16* bbase = Ftabt + (g * 64 + l15) * 64 + lk * 8;
#pragma unroll
        for (int nt = 0; nt < 4; ++nt)
#pragma unroll
            for (int ks = 0; ks < 2; ++ks) {
                const f16x8 b = *(const f16x8*)(bbase + nt * 1024 + ks * 32);
#pragma unroll
                for (int mt = 0; mt < 2; ++mt)
                    acc[mt][nt] = __builtin_amdgcn_mfma_f32_16x16x32_f16(
                        a[mt][ks], b, acc[mt][nt], 0, 0, 0);
            }

#pragma unroll
        for (int mt = 0; mt < 2; ++mt)
#pragma unroll
            for (int nt = 0; nt < 4; ++nt) {
                float* o = obase + (mt * 16 + lk * 4) * 256 + g * 64 + nt * 16 + l15;
#pragma unroll
                for (int r = 0; r < 4; ++r)
                    o[r * 256] = acc[mt][nt][r] * 0x1p-16f;
            }
    }
}

extern "C" void kernel_launch(void* const* d_in, const int* in_sizes, int n_in,
                              void* d_out, int out_size, void* d_ws, size_t ws_size,
                              hipStream_t stream) {
    (void)in_sizes; (void)n_in; (void)out_size; (void)ws_size;
    const float* x   = (const float*)d_in[0];
    const float* fs  = (const float*)d_in[1];
    const float* w0  = (const float*)d_in[2];
    const float* w1  = (const float*)d_in[3];
    const float* we0 = (const float*)d_in[4];
    const float* we1 = (const float*)d_in[5];
    float* out = (float*)d_out;
    float* ws = (float*)d_ws;

    f16* Etab   = (f16*)ws;                                // 64 KB
    f16* Ftabt  = (f16*)(ws + 16384);                      // 32 KB
    f16* Etab2  = (f16*)(ws + 24576);                      // 64 KB
    f16* Tt     = (f16*)(ws + 40960);                      // 32 KB
    f16* Xw16   = (f16*)(ws + 49152);                      // 16 MB
    f16* Gbuf   = (f16*)(ws + 49152 + 4194304);            // 16 MB
    f16* Xf16   = (f16*)(ws + 49152 + 8388608);            // 8 MB packed [p][j][kx]
    f16* Ff16   = (f16*)(ws + 49152 + 8388608 + 2097152);  // 8 MB packed [q][j][kx]

    k_tabs   <<<256,  128, 0, stream>>>(Etab, Ftabt, Etab2, Tt);
    k_rowdftB<<<1024, 256, 0, stream>>>(x, Tt, Xw16);
    k_coldftB<<<512,  256, 0, stream>>>(Xw16, Etab2, Xf16);
    k_mixB   <<<512,  256, 0, stream>>>(Xf16, fs, w0, w1, we0, we1, Ff16);
    k_invB   <<<512,  256, 0, stream>>>(Ff16, Etab, Gbuf);
    k_invC   <<<1024, 256, 0, stream>>>(Gbuf, Ftabt, out);
}

// Round 4
// 301.057 us; speedup vs baseline: 1.6322x; 1.0619x over previous
//
#include <hip/hip_runtime.h>

// Problem constants
// B=16, CI=CO=32, H=W=256, K0=K1=M=32, KAPPA=8, NPARA=7
// Kept modes: ky rows j in [0,64): ky = j (j<32) or j-64 (j>=32); kx cols 0..31
//
// Pipeline (raw/unnormalized DFTs; 1/65536 ortho factor applied at final store):
//  K1 (k_fwd, f16 MFMA):  per p=(b,ci): row-DFT (x -> Xw in LDS, sign-expanded)
//                         then col-DFT -> Xf16[p][j][kx] packed f16
//  K2 (k_mixB, f32 VALU): Ff16[q][j][kx] = sum_ci Xf16 * (W + s_b*We)
//  K3 (k_invF, f16 MFMA): per q: G[h][2kx+c] = sum_j Ff16 * e^{+i...} (LDS only),
//                         then out[q][h][w] = (1/65536) * sum_col G * Ftab

typedef _Float16 f16;
typedef _Float16 f16x8 __attribute__((ext_vector_type(8)));
typedef float f32x4 __attribute__((ext_vector_type(4)));

static __device__ __forceinline__ float2 upk(uint u) {
    union { uint x; f16 h[2]; } c; c.x = u;
    return make_float2((float)c.h[0], (float)c.h[1]);
}
static __device__ __forceinline__ uint pk2(float r, float i) {
    union { uint x; f16 h[2]; } c; c.h[0] = (f16)r; c.h[1] = (f16)i;
    return c.x;
}

// Tables:
//  Etab [h][2j]    = cos(2*pi*ky_j*h/256), [2j+1] = sin(...)     [256][128] f16 (invF B-phase A)
//  Ftabt[w][2k]    = c_k*cos(2*pi*k*w/256), [2k+1] = -c_k*sin()  [256][64]  f16 (invF C-phase B)
//  Etab2[j][h]     = cos(2*pi*ky_j*h/256)  (PLANAR K: cos plane) [64][512]  f16 (fwd col A)
//       [j][256+h] = sin(2*pi*ky_j*h/256)  (sin plane)
//  Tt  [2kx][w]    = cos(2*pi*kx*w/256), [2kx+1][w] = -sin(...)  [64][256]  f16 (fwd row B^T)
__global__ void k_tabs(f16* __restrict__ Etab, f16* __restrict__ Ftabt,
                       f16* __restrict__ Etab2, f16* __restrict__ Tt) {
    const int h = blockIdx.x;     // 0..255 (plays w where relevant)
    const int tid = threadIdx.x;  // 0..127
    if (tid < 64) {
        const int j = tid;
        const int ky = (j < 32) ? j : j - 64;
        float s, c;
        sincospif((float)(ky * h) / 128.0f, &s, &c);
        Etab[h * 128 + 2 * j] = (f16)c;
        Etab[h * 128 + 2 * j + 1] = (f16)s;
        Etab2[j * 512 + h] = (f16)c;        // cos plane (K = h)
        Etab2[j * 512 + 256 + h] = (f16)s;  // sin plane (K = 256+h)
    } else if (tid < 96) {
        const int k = tid - 64;
        const float ck = (k == 0) ? 1.0f : 2.0f;
        float s, c;
        sincospif((float)(k * h) / 128.0f, &s, &c);
        Ftabt[h * 64 + 2 * k] = (f16)(ck * c);
        Ftabt[h * 64 + 2 * k + 1] = (f16)(-ck * s);
    } else {
        const int kx = tid - 96;
        float s, c;
        sincospif((float)(kx * h) / 128.0f, &s, &c);
        Tt[(2 * kx) * 256 + h] = (f16)c;
        Tt[(2 * kx + 1) * 256 + h] = (f16)(-s);
    }
}

// K1 (k_fwd): fused row+col DFT per p=(b,ci). 512 blocks x 256 threads (= 2 blocks/CU).
// Phase 1: Xw[256h x 64n] = x[256h x 256w] * Tt^T, D-frags scattered to LDS Bt
//          in the planar sign-expanded col-DFT B layout:
//   Bt[2kx][h] = Xr[h], Bt[2kx][256+h] = Xi[h], Bt[2kx+1][h] = Xi[h], Bt[2kx+1][256+h] = -Xr[h]
// Phase 2: Xf[64j x 64n] = Etab2[64j x 512K] * Bt[64n x 512K]^T
//   Re = sum_h Xr*cos + Xi*sin ; Im = sum_h Xi*cos - Xr*sin    (e^{-i*theta})
__global__ __launch_bounds__(256) void k_fwd(const float* __restrict__ x,
                                             const f16* __restrict__ Tt,
                                             const f16* __restrict__ Etab2,
                                             f16* __restrict__ Xf16) {
    __shared__ __align__(16) f16 Bt[64 * 520];  // 66.6 KB, row stride 520 f16 (65x16B)
    const int tid = threadIdx.x;
    const long p = blockIdx.x;
    const int wv = tid >> 6, lane = tid & 63;
    const int l15 = lane & 15, lk = lane >> 4;

    // ---- Phase 1: row DFT (wave handles 64 h-rows = 4 m-tiles) ----
    {
        f32x4 acc[4][4];
#pragma unroll
        for (int mt = 0; mt < 4; ++mt)
#pragma unroll
            for (int nt = 0; nt < 4; ++nt)
                acc[mt][nt] = (f32x4){0.0f, 0.0f, 0.0f, 0.0f};

        const float* xbase = x + (p * 256 + wv * 64 + l15) * 256 + lk * 8;
        const f16* tbase = Tt + l15 * 256 + lk * 8;

#pragma unroll 4
        for (int ks = 0; ks < 8; ++ks) {
            f16x8 a[4], b[4];
#pragma unroll
            for (int mt = 0; mt < 4; ++mt) {
                const float4 u = *(const float4*)(xbase + mt * 4096 + ks * 32);
                const float4 v = *(const float4*)(xbase + mt * 4096 + ks * 32 + 4);
                a[mt][0] = (f16)u.x; a[mt][1] = (f16)u.y;
                a[mt][2] = (f16)u.z; a[mt][3] = (f16)u.w;
                a[mt][4] = (f16)v.x; a[mt][5] = (f16)v.y;
                a[mt][6] = (f16)v.z; a[mt][7] = (f16)v.w;
            }
#pragma unroll
            for (int nt = 0; nt < 4; ++nt)
                b[nt] = *(const f16x8*)(tbase + nt * 4096 + ks * 32);
#pragma unroll
            for (int mt = 0; mt < 4; ++mt)
#pragma unroll
                for (int nt = 0; nt < 4; ++nt)
                    acc[mt][nt] = __builtin_amdgcn_mfma_f32_16x16x32_f16(
                        a[mt], b[nt], acc[mt][nt], 0, 0, 0);
        }

        // scatter D -> Bt (planar layout). Lane owns n = nt*16+l15,
        // h = wv*64 + mt*16 + lk*4 + r  (r=0..3 consecutive -> packed b64 writes).
        const int n = l15;  // + nt*16 below
        const uint m = (n & 1) ? 0u : 0x80008000u;  // write2 sign: even n stores -v
#pragma unroll
        for (int mt = 0; mt < 4; ++mt) {
            const int H0 = wv * 64 + mt * 16 + lk * 4;
#pragma unroll
            for (int nt = 0; nt < 4; ++nt) {
                const int nn = nt * 16 + l15;
                const uint p0 = pk2(acc[mt][nt][0], acc[mt][nt][1]);
                const uint p1 = pk2(acc[mt][nt][2], acc[mt][nt][3]);
                *(uint2*)(Bt + nn * 520 + H0) = make_uint2(p0, p1);
                *(uint2*)(Bt + (nn ^ 1) * 520 + 256 + H0) = make_uint2(p0 ^ m, p1 ^ m);
            }
        }
    }
    __syncthreads();

    // ---- Phase 2: col DFT (wave handles 16 j-rows) ----
    {
        f32x4 acc[4];
#pragma unroll
        for (int nt = 0; nt < 4; ++nt) acc[nt] = (f32x4){0.0f, 0.0f, 0.0f, 0.0f};

        const f16* abase = Etab2 + (wv * 16 + l15) * 512 + lk * 8;  // global, L2-hot
#pragma unroll
        for (int ks = 0; ks < 16; ++ks) {
            const f16x8 a = *(const f16x8*)(abase + ks * 32);
            f16x8 b[4];
#pragma unroll
            for (int nt = 0; nt < 4; ++nt)
                b[nt] = *(const f16x8*)(Bt + (nt * 16 + l15) * 520 + ks * 32 + lk * 8);
#pragma unroll
            for (int nt = 0; nt < 4; ++nt)
                acc[nt] = __builtin_amdgcn_mfma_f32_16x16x32_f16(a, b[nt], acc[nt], 0, 0, 0);
        }

        f16* obase = Xf16 + p * 4096;
#pragma unroll
        for (int nt = 0; nt < 4; ++nt)
#pragma unroll
            for (int r = 0; r < 4; ++r)
                obase[(wv * 16 + lk * 4 + r) * 64 + nt * 16 + l15] = (f16)acc[nt][r];
    }
}

// K2 (mixB): block = (cog 8)*(corner 2)*(jj 32) = 512 blocks.
//   Ff[q=(b, cog*4+co)][j][kx] = sum_ci Xf[(b,ci)][j][kx] * (W + s(b,jj,kx)*We)
// Weight slice (64 KB f32) staged in LDS, read ONCE, coalesced; XOR-16 float4 swizzle.
__global__ __launch_bounds__(256) void k_mixB(const f16* __restrict__ Xf16,
                                              const float* __restrict__ fs,
                                              const float* __restrict__ w0,
                                              const float* __restrict__ w1,
                                              const float* __restrict__ we0,
                                              const float* __restrict__ we1,
                                              f16* __restrict__ Ff16) {
    __shared__ __align__(16) float4 Wl[4096];  // 64 KB: rows 0..127 = W, 128..255 = We
    const int tid = threadIdx.x;
    const int bid = blockIdx.x;
    const int cog = bid >> 6;            // 0..7 (co group of 4)
    const int corner = (bid >> 5) & 1;
    const int jj = bid & 31;
    const int j = corner * 32 + jj;

    {   // stage: t = tid>>7 (0:W 1:We), ci = (tid>>2)&31, co = tid&3
        const int t = tid >> 7, ci = (tid >> 2) & 31, co = tid & 3;
        const float* Wt = (t == 0) ? (corner ? w1 : w0) : (corner ? we1 : we0);
        const float4* src =
            (const float4*)(Wt + ((long)(ci * 32 + cog * 4 + co) * 2048 + jj * 64));
        const int m = tid & 15;
#pragma unroll
        for (int i = 0; i < 16; ++i) Wl[tid * 16 + (i ^ m)] = src[i];
    }
    __syncthreads();

    const int b = tid >> 4, kxp = tid & 15;
    const int kx0 = 2 * kxp;

    float s[2];
#pragma unroll
    for (int e = 0; e < 2; ++e) {
        const int v = kx0 + e, u = jj;
        int idx;
        if (u < 8 && v < 8) idx = 0;
        else if (u < 16 && v < 16) idx = (u < 8) ? 1 : ((v < 8) ? 2 : 3);
        else idx = (u < 16) ? 4 : ((v < 16) ? 5 : 6);
        s[e] = fs[b * 7 + idx];
    }

    float aW[4][4] = {}, aE[4][4] = {};  // [co][{re0,im0,re1,im1}]
    const uint* xb = (const uint*)Xf16 + (long)(b * 32) * 2048 + j * 32 + kxp * 2;

    for (int ci = 0; ci < 32; ++ci) {
        const uint2 xu = *(const uint2*)(xb + ci * 2048);
        const float2 x0 = upk(xu.x), x1 = upk(xu.y);
        const int rbase = ci * 4;
#pragma unroll
        for (int co = 0; co < 4; ++co) {
            const int rw = rbase + co;
            const int sl = kxp ^ (rw & 15);
            const float4 wv = Wl[rw * 16 + sl];
            const float4 ev = Wl[(128 + rw) * 16 + sl];
            aW[co][0] += x0.x * wv.x - x0.y * wv.y;
            aW[co][1] += x0.x * wv.y + x0.y * wv.x;
            aW[co][2] += x1.x * wv.z - x1.y * wv.w;
            aW[co][3] += x1.x * wv.w + x1.y * wv.z;
            aE[co][0] += x0.x * ev.x - x0.y * ev.y;
            aE[co][1] += x0.x * ev.y + x0.y * ev.x;
            aE[co][2] += x1.x * ev.z - x1.y * ev.w;
            aE[co][3] += x1.x * ev.w + x1.y * ev.z;
        }
    }

    uint* ofb = (uint*)Ff16;
#pragma unroll
    for (int co = 0; co < 4; ++co) {
        const long q = b * 32 + cog * 4 + co;
        uint2 o;
        o.x = pk2(aW[co][0] + s[0] * aE[co][0], aW[co][1] + s[0] * aE[co][1]);
        o.y = pk2(aW[co][2] + s[1] * aE[co][2], aW[co][3] + s[1] * aE[co][3]);
        *(uint2*)(ofb + q * 2048 + j * 32 + kxp * 2) = o;
    }
}

// K3 (invF): fused inverse per q. 512 blocks x 256 threads (= 2 blocks/CU).
// Phase B: G[256h x 64n] = Etab[256h x 128K] * F'[128K x 64n]  (F' realified from Ff16)
//          G kept in LDS only (f16, [h][col] stride 72).
// Phase C: out[256h x 256w] = (1/65536) * G[256h x 64col] * Ftab[64col x 256w]
__global__ __launch_bounds__(256) void k_invF(const f16* __restrict__ Ff16,
                                              const f16* __restrict__ Etab,
                                              const f16* __restrict__ Ftabt,
                                              float* __restrict__ out) {
    __shared__ __align__(16) f16 Ft[64 * 136];   // F' transposed [n][K], pad 128->136
    __shared__ __align__(16) f16 Gs[256 * 72];   // G [h][col], pad 64->72
    const int tid = threadIdx.x;
    const long q = blockIdx.x;
    const int wv = tid >> 6, lane = tid & 63;
    const int l15 = lane & 15, lk = lane >> 4;

    {   // stage F't from packed Ff16 (2048 u32 per q): thread handles 8 u32
        const uint4* src = (const uint4*)(Ff16 + q * 4096);
        uint* B32 = (uint*)Ft;
#pragma unroll
        for (int i = 0; i < 2; ++i) {
            const uint4 v = src[tid * 2 + i];
            const uint a4[4] = {v.x, v.y, v.z, v.w};
#pragma unroll
            for (int c = 0; c < 4; ++c) {
                const int idx = tid * 8 + i * 4 + c;  // u32 idx: j = idx>>5, kx = idx&31
                const int jr = idx >> 5, kx = idx & 31;
                const uint a = a4[c];
                B32[(2 * kx) * 68 + jr] = a ^ 0x80000000u;           // (re, -im)
                B32[(2 * kx + 1) * 68 + jr] = (a >> 16) | (a << 16); // (im,  re)
            }
        }
    }
    __syncthreads();

    // ---- Phase B ----
    {
        f32x4 acc[4][4];
#pragma unroll
        for (int mt = 0; mt < 4; ++mt)
#pragma unroll
            for (int nt = 0; nt < 4; ++nt)
                acc[mt][nt] = (f32x4){0.0f, 0.0f, 0.0f, 0.0f};

        const f16* Arow = Etab + (wv * 64 + l15) * 128 + lk * 8;  // global, L2-hot
#pragma unroll
        for (int ks = 0; ks < 4; ++ks) {
            f16x8 a[4], b[4];
#pragma unroll
            for (int mt = 0; mt < 4; ++mt)
                a[mt] = *(const f16x8*)(Arow + mt * 2048 + ks * 32);
#pragma unroll
            for (int nt = 0; nt < 4; ++nt)
                b[nt] = *(const f16x8*)(&Ft[(nt * 16 + l15) * 136 + ks * 32 + lk * 8]);
#pragma unroll
            for (int mt = 0; mt < 4; ++mt)
#pragma unroll
                for (int nt = 0; nt < 4; ++nt)
                    acc[mt][nt] = __builtin_amdgcn_mfma_f32_16x16x32_f16(
                        a[mt], b[nt], acc[mt][nt], 0, 0, 0);
        }

#pragma unroll
        for (int mt = 0; mt < 4; ++mt)
#pragma unroll
            for (int nt = 0; nt < 4; ++nt) {
                const int row = wv * 64 + mt * 16 + lk * 4;
                const int col = nt * 16 + l15;
#pragma unroll
                for (int r = 0; r < 4; ++r)
                    Gs[(row + r) * 72 + col] = (f16)acc[mt][nt][r];
            }
    }
    __syncthreads();

    // ---- Phase C: wave handles h-block wv*64..+63, all 256 w in 4 groups ----
    {
        const int hb = wv * 64;
        f16x8 a[4][2];
#pragma unroll
        for (int mt = 0; mt < 4; ++mt)
#pragma unroll
            for (int ks = 0; ks < 2; ++ks)
                a[mt][ks] = *(const f16x8*)(Gs + (hb + mt * 16 + l15) * 72 + ks * 32 + lk * 8);

        float* obase = out + q * 65536 + (long)hb * 256;

#pragma unroll 1
        for (int g = 0; g < 4; ++g) {  // 4 groups of 64 w-columns
            f32x4 acc[4][4];
#pragma unroll
            for (int mt = 0; mt < 4; ++mt)
#pragma unroll
                for (int nt = 0; nt < 4; ++nt)
                    acc[mt][nt] = (f32x4){0.0f, 0.0f, 0.0f, 0.0f};

            const f16* bbase = Ftabt + (g * 64 + l15) * 64 + lk * 8;
#pragma unroll
            for (int nt = 0; nt < 4; ++nt)
#pragma unroll
                for (int ks = 0; ks < 2; ++ks) {
                    const f16x8 b = *(const f16x8*)(bbase + nt * 1024 + ks * 32);
#pragma unroll
                    for (int mt = 0; mt < 4; ++mt)
                        acc[mt][nt] = __builtin_amdgcn_mfma_f32_16x16x32_f16(
                            a[mt][ks], b, acc[mt][nt], 0, 0, 0);
                }

#pragma unroll
            for (int mt = 0; mt < 4; ++mt)
#pragma unroll
                for (int nt = 0; nt < 4; ++nt) {
                    float* o = obase + (mt * 16 + lk * 4) * 256 + g * 64 + nt * 16 + l15;
#pragma unroll
                    for (int r = 0; r < 4; ++r)
                        o[r * 256] = acc[mt][nt][r] * 0x1p-16f;
                }
        }
    }
}

extern "C" void kernel_launch(void* const* d_in, const int* in_sizes, int n_in,
                              void* d_out, int out_size, void* d_ws, size_t ws_size,
                              hipStream_t stream) {
    (void)in_sizes; (void)n_in; (void)out_size; (void)ws_size;
    const float* x   = (const float*)d_in[0];
    const float* fs  = (const float*)d_in[1];
    const float* w0  = (const float*)d_in[2];
    const float* w1  = (const float*)d_in[3];
    const float* we0 = (const float*)d_in[4];
    const float* we1 = (const float*)d_in[5];
    float* out = (float*)d_out;
    float* ws = (float*)d_ws;

    f16* Etab   = (f16*)ws;                        // 64 KB
    f16* Ftabt  = (f16*)(ws + 16384);              // 32 KB
    f16* Etab2  = (f16*)(ws + 24576);              // 64 KB (planar cos/sin)
    f16* Tt     = (f16*)(ws + 40960);              // 32 KB
    f16* Xf16   = (f16*)(ws + 49152);              // 4 MB packed [p][j][kx]
    f16* Ff16   = (f16*)(ws + 49152 + 1048576);    // 4 MB packed [q][j][kx]

    k_tabs <<<256, 128, 0, stream>>>(Etab, Ftabt, Etab2, Tt);
    k_fwd  <<<512, 256, 0, stream>>>(x, Tt, Etab2, Xf16);
    k_mixB <<<512, 256, 0, stream>>>(Xf16, fs, w0, w1, we0, we1, Ff16);
    k_invF <<<512, 256, 0, stream>>>(Ff16, Etab, Ftabt, out);
}